// Round 1
// baseline (677.787 us; speedup 1.0000x reference)
//
#include <hip/hip_runtime.h>
#include <stdint.h>

// Forward warp (scatter bilinear splat), output-tile-owned gather-scatter.
// img: (N=4, C=3, H=1080, W=1920) fp32
// flo: (N, 2, H, W) fp32; plane0=y (drives COLUMN), plane1=x (drives ROW), per reference.
// out[n, c, h+floor(x)+dx, w+floor(y)+dy] += img[n,c,h,w] * wx*wy
//
// kernel1: each block owns a disjoint 64x32 OUTPUT tile; scans sources in the
// tile+HALO window, splats into an LDS accumulator via NATIVE ds_add_f32
// (inline asm -- HIP atomicAdd on shared float may lower to a CAS loop),
// then plain-stores the tile (each output cell written exactly once).
// kernel2: exact fixup for contributions whose source lies outside the owning
// tile's window (|flow| > HALO, P~1e-4) via global atomics. float4-vectorized.

#define N_ 4
#define C_ 3
#define H_ 1080
#define W_ 1920
#define HW_ (H_ * W_)

#define TW 64
#define TH 32
#define HALO 4
#define WW (TW + 2 * HALO)  // 72
#define WH (TH + 2 * HALO)  // 40
#define TSZ (TW * TH)       // 2048 per channel

// Native LDS float atomic add, no return value (fire-and-forget).
// byte_off is the LDS byte offset (low 32 bits of the generic pointer to LDS:
// shared aperture is 4GB-aligned, so truncation yields the ds offset).
__device__ __forceinline__ void lds_fadd(uint32_t byte_off, float v) {
  asm volatile("ds_add_f32 %0, %1" : : "v"(byte_off), "v"(v));
}

__global__ __launch_bounds__(256) void fw_tile_kernel(
    const float* __restrict__ img, const float* __restrict__ flo,
    float* __restrict__ out) {
  __shared__ float s[C_ * TSZ];  // 24 KB -> 6 blocks/CU

  const int tid = threadIdx.x;
  const int W0 = blockIdx.x * TW;
  const int H0 = blockIdx.y * TH;
  const int n = blockIdx.z;
  const int base = n * C_ * HW_;

  // 1) zero LDS accumulator
  for (int i = tid; i < C_ * TSZ; i += 256) s[i] = 0.0f;
  __syncthreads();

  const uint32_t sb = (uint32_t)(uintptr_t)(&s[0]);

  // 2) gather-scatter over the source window (tile +- HALO)
  for (int i = tid; i < WH * WW; i += 256) {
    const int wy = i / WW;
    const int wx = i - wy * WW;
    const int h = H0 - HALO + wy;
    const int w = W0 - HALO + wx;
    if ((unsigned)h >= H_ || (unsigned)w >= W_) continue;
    const int hw = h * W_ + w;

    const float y = flo[(n * 2 + 0) * HW_ + hw];
    const float x = flo[(n * 2 + 1) * HW_ + hw];
    const float x1 = floorf(x);
    const float y1 = floorf(y);
    const int ix = (int)x1;
    const int iy = (int)y1;
    const float fx = x - x1;  // weight for dx==1 (row)
    const float fy = y - y1;  // weight for dy==1 (col)

    const float c0 = img[base + 0 * HW_ + hw];
    const float c1 = img[base + 1 * HW_ + hw];
    const float c2 = img[base + 2 * HW_ + hw];

    const int ty = wy - HALO;  // source pos, tile-local
    const int tx = wx - HALO;

#pragma unroll
    for (int dx = 0; dx < 2; ++dx) {
      const int lh = ty + ix + dx;
      const float wxw = dx ? fx : (1.0f - fx);
#pragma unroll
      for (int dy = 0; dy < 2; ++dy) {
        const int lw = tx + iy + dy;
        if ((unsigned)lh < TH && (unsigned)lw < TW) {
          const float wt = wxw * (dy ? fy : (1.0f - fy));
          const uint32_t o = sb + (uint32_t)(lh * TW + lw) * 4u;
          lds_fadd(o, c0 * wt);
          lds_fadd(o + TSZ * 4u, c1 * wt);
          lds_fadd(o + 2u * TSZ * 4u, c2 * wt);
        }
      }
    }
  }

  // drain our asm ds ops before the barrier (compiler can't see them)
  asm volatile("s_waitcnt lgkmcnt(0)" ::: "memory");
  __syncthreads();

  // 3) plain coalesced stores: each output cell owned by exactly one block
  for (int i = tid; i < C_ * TSZ; i += 256) {
    const int c = i >> 11;  // / 2048
    const int r = i & (TSZ - 1);
    const int ty = r >> 6;
    const int tx = r & (TW - 1);
    const int h = H0 + ty;
    if (h < H_) out[base + c * HW_ + h * W_ + (W0 + tx)] = s[i];
    // W_ divisible by TW -> no horizontal check needed
  }
}

// Fixup: contributions whose source pixel lies outside the owning tile's window.
// float4-vectorized fast reject: 4 pixels/thread, 16B/lane flo loads.
__global__ __launch_bounds__(256) void fw_fixup_kernel(
    const float* __restrict__ img, const float* __restrict__ flo,
    float* __restrict__ out) {
  const int t = blockIdx.x * blockDim.x + threadIdx.x;
  if (t >= (N_ * HW_) / 4) return;
  const int idx4 = t * 4;
  const int n = idx4 / HW_;
  const int hw4 = idx4 - n * HW_;  // HW_ % 4 == 0 -> all 4 px in same image

  const float4 yv =
      *reinterpret_cast<const float4*>(flo + (size_t)(n * 2 + 0) * HW_ + hw4);
  const float4 xv =
      *reinterpret_cast<const float4*>(flo + (size_t)(n * 2 + 1) * HW_ + hw4);

  const float ys[4] = {yv.x, yv.y, yv.z, yv.w};
  const float xs[4] = {xv.x, xv.y, xv.z, xv.w};

  // fast reject: floor(x) in [-HALO, HALO-1] <=> x in [-HALO, HALO)
  bool any = false;
#pragma unroll
  for (int k = 0; k < 4; ++k) {
    const bool inside = (xs[k] >= -(float)HALO) && (xs[k] < (float)HALO) &&
                        (ys[k] >= -(float)HALO) && (ys[k] < (float)HALO);
    any |= !inside;
  }
  if (!any) return;

  const int base = n * C_ * HW_;
#pragma unroll 1
  for (int k = 0; k < 4; ++k) {
    const float x = xs[k];
    const float y = ys[k];
    const bool inside = (x >= -(float)HALO) && (x < (float)HALO) &&
                        (y >= -(float)HALO) && (y < (float)HALO);
    if (inside) continue;  // all 4 targets covered by kernel1

    const int hw = hw4 + k;
    const int h = hw / W_;
    const int w = hw - h * W_;
    const float x1 = floorf(x);
    const float y1 = floorf(y);
    const int ix = (int)x1;
    const int iy = (int)y1;
    const float fx = x - x1;
    const float fy = y - y1;
    const float c0 = img[base + 0 * HW_ + hw];
    const float c1 = img[base + 1 * HW_ + hw];
    const float c2 = img[base + 2 * HW_ + hw];

#pragma unroll
    for (int dx = 0; dx < 2; ++dx) {
      const int dh = h + ix + dx;
      if ((unsigned)dh >= H_) continue;
      const float wxw = dx ? fx : (1.0f - fx);
#pragma unroll
      for (int dy = 0; dy < 2; ++dy) {
        const int dw = w + iy + dy;
        if ((unsigned)dw >= W_) continue;
        // owning tile of target, and its source window
        const int wy0 = (dh / TH) * TH - HALO;
        const int wx0 = (dw / TW) * TW - HALO;
        const bool in_window = (h >= wy0) && (h < wy0 + WH) && (w >= wx0) &&
                               (w < wx0 + WW);
        if (in_window) continue;  // kernel1 already added this contribution
        const float wt = wxw * (dy ? fy : (1.0f - fy));
        const int o = base + dh * W_ + dw;
        atomicAdd(out + o, c0 * wt);
        atomicAdd(out + o + HW_, c1 * wt);
        atomicAdd(out + o + 2 * HW_, c2 * wt);
      }
    }
  }
}

extern "C" void kernel_launch(void* const* d_in, const int* in_sizes, int n_in,
                              void* d_out, int out_size, void* d_ws,
                              size_t ws_size, hipStream_t stream) {
  const float* img = (const float*)d_in[0];
  const float* flo = (const float*)d_in[1];
  float* out = (float*)d_out;

  // No memset needed: fw_tile_kernel writes every output element exactly once.
  dim3 grid1(W_ / TW, (H_ + TH - 1) / TH, N_);  // 30 x 34 x 4
  fw_tile_kernel<<<grid1, 256, 0, stream>>>(img, flo, out);

  const int total4 = (N_ * HW_) / 4;
  fw_fixup_kernel<<<(total4 + 255) / 256, 256, 0, stream>>>(img, flo, out);
}